// Round 3
// baseline (1690.734 us; speedup 1.0000x reference)
//
#include <hip/hip_runtime.h>
#include <math.h>

#define G 4
#define H 64
#define T 1000
#define B 32
#define ROWS (B*T)  // 32000

__device__ __forceinline__ float sigm(float x) {
    return 1.f / (1.f + __expf(-x));
}
__device__ __forceinline__ float tanh_f(float x) {
    return 2.f / (1.f + __expf(-2.f * x)) - 1.f;
}

// ============================================================================
// xp projection GEMM: xp[g,b,t,k] = bias[g,k] + sum_i Wih[g,k,i] * x'[b,t,g,i]
// x' = a*x+c (fused BN, layer 2) or x (layer 1).
// Block computes a 64t x 64k tile; 256 threads as 16(tx=k-quad) x 16(ty=t-quad),
// each thread a 4x4 register tile. LDS tiles padded [64][68] -> conflict-free.
// Buffer slot for (g,b) is g*32+b.
// ============================================================================
template<bool BN>
__global__ __launch_bounds__(256)
void xp_proj(const float* __restrict__ xin,   // (B,T,256)
             const float* __restrict__ Wih,   // (G,256,64)
             const float* __restrict__ bias,  // (G,256)
             const float* __restrict__ ac,    // [512] a|c (BN only)
             float* __restrict__ xp,          // (128, tcmax, 256)
             int t0, int tcn, int tcmax, int TT)
{
    int id = blockIdx.x;
    const int kt = id & 3; id >>= 2;
    const int tt = id % TT; id /= TT;
    const int b = id & 31;
    const int g = id >> 5;

    __shared__ __align__(16) float xs[64][68];
    __shared__ __align__(16) float ws[64][68];

    const int tx = threadIdx.x & 15, ty = threadIdx.x >> 4;

    // stage W tile (rows kt*64 .. kt*64+63)
    #pragma unroll
    for (int j = 0; j < 4; ++j) {
        int idx = j * 1024 + threadIdx.x * 4;
        int r = idx >> 6, ci = idx & 63;
        float4 v = *(const float4*)&Wih[(size_t)((g * 256 + kt * 64 + r) << 6) + ci];
        *(float4*)&ws[r][ci] = v;
    }
    // stage x tile (rows t0+tt*64 .. +63), optional BN fold
    #pragma unroll
    for (int j = 0; j < 4; ++j) {
        int idx = j * 1024 + threadIdx.x * 4;
        int r = idx >> 6, ci = idx & 63;
        int tg = t0 + tt * 64 + r; if (tg > T - 1) tg = T - 1;
        float4 v = *(const float4*)&xin[((size_t)b * T + tg) * 256 + g * 64 + ci];
        if (BN) {
            float4 a4 = *(const float4*)&ac[g * 64 + ci];
            float4 c4 = *(const float4*)&ac[256 + g * 64 + ci];
            v.x = fmaf(v.x, a4.x, c4.x);
            v.y = fmaf(v.y, a4.y, c4.y);
            v.z = fmaf(v.z, a4.z, c4.z);
            v.w = fmaf(v.w, a4.w, c4.w);
        }
        *(float4*)&xs[r][ci] = v;
    }
    __syncthreads();

    float acc[4][4] = {};
    #pragma unroll
    for (int i4 = 0; i4 < 16; ++i4) {
        float4 xv[4], wv[4];
        #pragma unroll
        for (int q = 0; q < 4; ++q) xv[q] = *(const float4*)&xs[ty * 4 + q][i4 * 4];
        #pragma unroll
        for (int q = 0; q < 4; ++q) wv[q] = *(const float4*)&ws[tx * 4 + q][i4 * 4];
        #pragma unroll
        for (int a = 0; a < 4; ++a)
            #pragma unroll
            for (int c = 0; c < 4; ++c) {
                acc[a][c] = fmaf(xv[a].x, wv[c].x, acc[a][c]);
                acc[a][c] = fmaf(xv[a].y, wv[c].y, acc[a][c]);
                acc[a][c] = fmaf(xv[a].z, wv[c].z, acc[a][c]);
                acc[a][c] = fmaf(xv[a].w, wv[c].w, acc[a][c]);
            }
    }

    const int kbase = kt * 64 + tx * 4;
    const float4 b4 = *(const float4*)&bias[g * 256 + kbase];
    float* xpb = xp + (size_t)(g * 32 + b) * tcmax * 256;
    #pragma unroll
    for (int a = 0; a < 4; ++a) {
        int tloc = tt * 64 + ty * 4 + a;
        if (tloc < tcn) {
            float4 o;
            o.x = acc[a][0] + b4.x;
            o.y = acc[a][1] + b4.y;
            o.z = acc[a][2] + b4.z;
            o.w = acc[a][3] + b4.w;
            *(float4*)&xpb[(size_t)tloc * 256 + kbase] = o;
        }
    }
}

// ============================================================================
// Recurrence with precomputed xp. One block per (g,b). Gate-interleaved map:
// wave w owns cols w*16..w*16+15; lane l: gate gt=l>>4 of col w*16+(l&15).
// One barrier/step, double-buffered hsh, 4-slot rotating xp prefetch.
// xp buffer slot for (g,b) is g*32+b (MUST match xp_proj).
// ============================================================================
template<int LAYER>
__global__ __launch_bounds__(256, 1)
void rec_xp(const float* __restrict__ xp,     // (128, tcmax, 256)
            const float* __restrict__ Whh,    // (G,256,64)
            float* __restrict__ out,          // (B,T,256)
            float* __restrict__ stateh, float* __restrict__ statec,
            int t0, int t1, int tcmax)
{
    const int blk = blockIdx.x;
    const int g = blk & 3, b = blk >> 2;
    const int l  = threadIdx.x & 63;
    const int w  = threadIdx.x >> 6;
    const int gt = l >> 4, c16 = l & 15;
    const int col = w * 16 + c16;       // 0..63
    const int row = gt * 64 + col;      // gate row 0..255

    __shared__ __align__(16) float hsh[2][64];

    float whh[64];
    {
        const float4* wp = (const float4*)&Whh[(size_t)((g * 256 + row) << 6)];
        #pragma unroll
        for (int i = 0; i < 16; ++i) {
            float4 v = wp[i];
            whh[4*i] = v.x; whh[4*i+1] = v.y; whh[4*i+2] = v.z; whh[4*i+3] = v.w;
        }
    }
    // activation constants: gt==2 -> tanh = 2*sigm(2x)-1, else sigmoid
    const float m  = (gt == 2) ? 2.f : 1.f;
    const float A  = (gt == 2) ? 2.f : 1.f;
    const float Bc = (gt == 2) ? -1.f : 0.f;

    float cst;
    if (t0 == 0) {
        cst = 0.f;
        if (threadIdx.x < 64) hsh[0][threadIdx.x] = 0.f;
    } else {
        cst = statec[blk * 64 + col];
        if (threadIdx.x < 64) hsh[0][threadIdx.x] = stateh[blk * 64 + threadIdx.x];
    }

    const float* xpb = xp + (size_t)(g * 32 + b) * tcmax * 256 + row;  // slot g*32+b
    float p[4];
    #pragma unroll
    for (int j = 0; j < 4; ++j) {
        int tp = t0 + j; if (tp > t1 - 1) tp = t1 - 1;
        p[j] = xpb[(size_t)(tp - t0) * 256];
    }
    __syncthreads();

    float hl = 0.f;
    const int nsteps = t1 - t0;   // multiple of 4 by construction
    for (int s = 0; s < nsteps; s += 4) {
        #pragma unroll
        for (int j = 0; j < 4; ++j) {
            const int cur = j & 1;
            // h-matvec (broadcast LDS reads, 4 accumulators)
            float a0 = 0.f, a1 = 0.f, a2 = 0.f, a3 = 0.f;
            const float4* hv = (const float4*)hsh[cur];
            #pragma unroll
            for (int q = 0; q < 16; ++q) {
                float4 z = hv[q];
                a0 = fmaf(whh[4*q],   z.x, a0);
                a1 = fmaf(whh[4*q+1], z.y, a1);
                a2 = fmaf(whh[4*q+2], z.z, a2);
                a3 = fmaf(whh[4*q+3], z.w, a3);
            }
            float acc = p[j] + ((a0 + a1) + (a2 + a3));  // xp includes bias
            // refill slot j for step s+j+4 (used 4 steps later -> latency hidden)
            {
                int tp = t0 + s + j + 4; if (tp > t1 - 1) tp = t1 - 1;
                p[j] = xpb[(size_t)(tp - t0) * 256];
            }
            float act = A / (1.f + __expf(-m * acc)) + Bc;
            // gather i,f,g,o for this lane's column (intra-wave shuffles)
            float ig = __shfl(act, c16);
            float fg = __shfl(act, c16 + 16);
            float gg = __shfl(act, c16 + 32);
            float og = __shfl(act, c16 + 48);
            cst = fmaf(fg, cst, ig * gg);
            float h = og * tanh_f(cst);
            if (gt == 0) {
                hsh[cur ^ 1][col] = h;
                int t = t0 + s + j;
                if (LAYER == 1) out[((size_t)b * T + t) * 256 + col * 4 + g] = h;
                else            out[((size_t)b * T + t) * 256 + g * 64 + col] = h;
            }
            hl = h;
            __syncthreads();
        }
    }
    if (gt == 0) {
        stateh[blk * 64 + col] = hl;
        statec[blk * 64 + col] = cst;
    }
}

// ============================================================================
// Fallback (proven round-1): fused rec kernel, used only if ws is too small.
// ============================================================================
template<int LAYER>
__global__ __launch_bounds__(256, 1)
void rec_kernel(const float* __restrict__ xin,
                const float* __restrict__ Wih,
                const float* __restrict__ Whh,
                const float* __restrict__ bias,
                const float* __restrict__ bnac,
                float* __restrict__ out)
{
    const int g = blockIdx.x & 3;
    const int b = blockIdx.x >> 2;
    const int k = threadIdx.x;

    __shared__ __align__(16) float xsh[2][64];
    __shared__ __align__(16) float hsh[64];
    __shared__ __align__(16) float gsh[256];

    float wih[64], whh[64];
    {
        const float4* wi = (const float4*)(Wih + (size_t)(g * 256 + k) * 64);
        const float4* wh = (const float4*)(Whh + (size_t)(g * 256 + k) * 64);
        #pragma unroll
        for (int i = 0; i < 16; ++i) {
            float4 v = wi[i];
            wih[4*i] = v.x; wih[4*i+1] = v.y; wih[4*i+2] = v.z; wih[4*i+3] = v.w;
            float4 u = wh[i];
            whh[4*i] = u.x; whh[4*i+1] = u.y; whh[4*i+2] = u.z; whh[4*i+3] = u.w;
        }
    }
    const float bk = bias[g * 256 + k];
    const long rowbase = (long)b * T;
    const int  colbase = g * 64;

    float c = 0.f, af = 1.f, cf = 0.f;
    float xa = 0.f, xb = 0.f;

    if (k < 64) {
        if (LAYER == 2) { af = bnac[colbase + k]; cf = bnac[256 + colbase + k]; }
        hsh[k] = 0.f;
        float x0 = xin[(rowbase + 0) * 256 + colbase + k];
        xsh[0][k] = (LAYER == 2) ? fmaf(x0, af, cf) : x0;
        xa = xin[(rowbase + 1) * 256 + colbase + k];
        xb = xin[(rowbase + 2) * 256 + colbase + k];
    }
    __syncthreads();

    for (int t = 0; t < T; ++t) {
        const int cur = t & 1;
        float xn = 0.f;
        if (k < 64) {
            int tp = t + 3; if (tp > T - 1) tp = T - 1;
            xn = xin[(rowbase + tp) * 256 + colbase + k];
        }
        const float* xs = xsh[cur];
        float a0 = 0.f, a1 = 0.f, a2 = 0.f, a3 = 0.f;
        #pragma unroll
        for (int i = 0; i < 64; i += 4) {
            a0 = fmaf(wih[i],     xs[i],     a0);
            a1 = fmaf(wih[i + 1], xs[i + 1], a1);
            a2 = fmaf(wih[i + 2], xs[i + 2], a2);
            a3 = fmaf(wih[i + 3], xs[i + 3], a3);
        }
        #pragma unroll
        for (int jq = 0; jq < 64; jq += 4) {
            a0 = fmaf(whh[jq],     hsh[jq],     a0);
            a1 = fmaf(whh[jq + 1], hsh[jq + 1], a1);
            a2 = fmaf(whh[jq + 2], hsh[jq + 2], a2);
            a3 = fmaf(whh[jq + 3], hsh[jq + 3], a3);
        }
        const float acc = bk + ((a0 + a1) + (a2 + a3));
        const float act = (k >= 128 && k < 192) ? tanh_f(acc) : sigm(acc);
        gsh[k] = act;
        __syncthreads();

        if (k < 64) {
            const float ig = gsh[k];
            const float fg = gsh[64 + k];
            const float gg = gsh[128 + k];
            const float og = gsh[192 + k];
            c = fmaf(fg, c, ig * gg);
            const float h = og * tanh_f(c);
            hsh[k] = h;
            const long rrow = rowbase + t;
            if (LAYER == 1) out[rrow * 256 + k * 4 + g] = h;
            else            out[rrow * 256 + colbase + k] = h;
            xsh[cur ^ 1][k] = fmaf(xa, af, cf);
            xa = xb; xb = xn;
        }
        __syncthreads();
    }
}

// ============================================================================
// BN stats / apply
// ============================================================================
__global__ void zero_ws(float* sums) {
    int i = blockIdx.x * blockDim.x + threadIdx.x;
    if (i < 512) sums[i] = 0.f;
}

__global__ __launch_bounds__(256) void stats_reduce(const float* __restrict__ x,
                                                    float* __restrict__ sums)
{
    float s = 0.f, ss = 0.f;
    for (int r = blockIdx.x; r < ROWS; r += gridDim.x) {
        float v = x[(long)r * 256 + threadIdx.x];
        s += v;
        ss = fmaf(v, v, ss);
    }
    atomicAdd(&sums[threadIdx.x], s);
    atomicAdd(&sums[256 + threadIdx.x], ss);
}

__global__ void stats_finalize(const float* __restrict__ sums,
                               const float* __restrict__ gamma,
                               const float* __restrict__ beta,
                               float* __restrict__ ac)
{
    int f = threadIdx.x;
    const float invN = 1.f / (float)ROWS;
    float mean = sums[f] * invN;
    float var  = fmaf(-mean, mean, sums[256 + f] * invN);
    float a = gamma[f] * rsqrtf(var + 1e-5f);
    ac[f]       = a;
    ac[256 + f] = fmaf(-mean, a, beta[f]);
}

__global__ __launch_bounds__(256) void bn_apply(float* __restrict__ x,
                                                const float* __restrict__ ac)
{
    __shared__ float a_s[256], c_s[256];
    a_s[threadIdx.x] = ac[threadIdx.x];
    c_s[threadIdx.x] = ac[256 + threadIdx.x];
    __syncthreads();
    const long n4 = (long)ROWS * 64;
    for (long i = (long)blockIdx.x * blockDim.x + threadIdx.x; i < n4;
         i += (long)gridDim.x * blockDim.x) {
        float4 v = ((float4*)x)[i];
        int f0 = (int)((i * 4) & 255);
        v.x = fmaf(v.x, a_s[f0],     c_s[f0]);
        v.y = fmaf(v.y, a_s[f0 + 1], c_s[f0 + 1]);
        v.z = fmaf(v.z, a_s[f0 + 2], c_s[f0 + 2]);
        v.w = fmaf(v.w, a_s[f0 + 3], c_s[f0 + 3]);
        ((float4*)x)[i] = v;
    }
}

extern "C" void kernel_launch(void* const* d_in, const int* in_sizes, int n_in,
                              void* d_out, int out_size, void* d_ws, size_t ws_size,
                              hipStream_t stream)
{
    const float* inpt   = (const float*)d_in[0];
    const float* Wih1   = (const float*)d_in[1];
    const float* Whh1   = (const float*)d_in[2];
    const float* b1     = (const float*)d_in[3];
    const float* Wih2   = (const float*)d_in[4];
    const float* Whh2   = (const float*)d_in[5];
    const float* b2     = (const float*)d_in[6];
    const float* gamma1 = (const float*)d_in[7];
    const float* beta1  = (const float*)d_in[8];
    const float* gamma2 = (const float*)d_in[9];
    const float* beta2  = (const float*)d_in[10];
    float* out  = (float*)d_out;

    float* sums = (float*)d_ws;       // 512
    float* acbn = sums + 512;         // 512
    float* sth  = acbn + 512;         // 8192 (128*64)
    float* stc  = sth + 8192;         // 8192
    float* xpb  = stc + 8192;         // chunk buffer

    const size_t fixedB = (size_t)(512 + 512 + 8192 + 8192) * 4;  // 69632
    long availT = ((long)ws_size - (long)fixedB) / (128L * 256L * 4L);
    int Tcmax = (availT >= T) ? T : (int)(availT & ~3L);

    if (Tcmax >= 100) {
        // ---- layer 1
        zero_ws<<<2, 256, 0, stream>>>(sums);
        for (int t0 = 0; t0 < T; t0 += Tcmax) {
            int tcn = T - t0; if (tcn > Tcmax) tcn = Tcmax;
            int TT = (tcn + 63) / 64;
            xp_proj<false><<<128 * TT * 4, 256, 0, stream>>>(
                inpt, Wih1, b1, nullptr, xpb, t0, tcn, Tcmax, TT);
            rec_xp<1><<<128, 256, 0, stream>>>(xpb, Whh1, out, sth, stc, t0, t0 + tcn, Tcmax);
        }
        stats_reduce<<<256, 256, 0, stream>>>(out, sums);
        stats_finalize<<<1, 256, 0, stream>>>(sums, gamma1, beta1, acbn);

        // ---- layer 2 (BN1 fused into xp staging)
        for (int t0 = 0; t0 < T; t0 += Tcmax) {
            int tcn = T - t0; if (tcn > Tcmax) tcn = Tcmax;
            int TT = (tcn + 63) / 64;
            xp_proj<true><<<128 * TT * 4, 256, 0, stream>>>(
                out, Wih2, b2, acbn, xpb, t0, tcn, Tcmax, TT);
            rec_xp<2><<<128, 256, 0, stream>>>(xpb, Whh2, out, sth, stc, t0, t0 + tcn, Tcmax);
        }
        zero_ws<<<2, 256, 0, stream>>>(sums);
        stats_reduce<<<256, 256, 0, stream>>>(out, sums);
        stats_finalize<<<1, 256, 0, stream>>>(sums, gamma2, beta2, acbn);
        bn_apply<<<2048, 256, 0, stream>>>(out, acbn);
    } else {
        // ---- fallback: round-1 monolithic path (ws only needs 4 KB)
        zero_ws<<<2, 256, 0, stream>>>(sums);
        rec_kernel<1><<<G * B, 256, 0, stream>>>(inpt, Wih1, Whh1, b1, nullptr, out);
        stats_reduce<<<256, 256, 0, stream>>>(out, sums);
        stats_finalize<<<1, 256, 0, stream>>>(sums, gamma1, beta1, acbn);
        rec_kernel<2><<<G * B, 256, 0, stream>>>(out, Wih2, Whh2, b2, acbn, out);
        zero_ws<<<2, 256, 0, stream>>>(sums);
        stats_reduce<<<256, 256, 0, stream>>>(out, sums);
        stats_finalize<<<1, 256, 0, stream>>>(sums, gamma2, beta2, acbn);
        bn_apply<<<2048, 256, 0, stream>>>(out, acbn);
    }
}

// Round 4
// 1536.368 us; speedup vs baseline: 1.1005x; 1.1005x over previous
//
#include <hip/hip_runtime.h>
#include <math.h>

#define G 4
#define H 64
#define T 1000
#define B 32
#define ROWS (B*T)  // 32000

__device__ __forceinline__ float sigm(float x) {
    return 1.f / (1.f + __expf(-x));
}
__device__ __forceinline__ float tanh_f(float x) {
    return 2.f / (1.f + __expf(-2.f * x)) - 1.f;
}

// ============================================================================
// xp projection GEMM: xp[g,b,t,k] = bias[g,k] + sum_i Wih[g,k,i] * x'[b,t,g,i]
// One block = 64t x 256k for one (g,b,tt): x tile staged ONCE, kt=0..3 looped
// (W restaged per kt). 256 threads as 16x16, 4x4 register tile each.
// Buffer slot for (g,b) is g*32+b.
// ============================================================================
template<bool BN>
__global__ __launch_bounds__(256)
void xp_proj(const float* __restrict__ xin,   // (B,T,256)
             const float* __restrict__ Wih,   // (G,256,64)
             const float* __restrict__ bias,  // (G,256)
             const float* __restrict__ ac,    // [512] a|c (BN only)
             float* __restrict__ xp,          // (128, tcmax, 256)
             int t0, int tcn, int tcmax, int TT)
{
    int id = blockIdx.x;
    const int tt = id % TT; id /= TT;
    const int b = id & 31;
    const int g = id >> 5;

    __shared__ __align__(16) float xs[64][68];
    __shared__ __align__(16) float ws[64][68];

    const int tx = threadIdx.x & 15, ty = threadIdx.x >> 4;

    // stage x tile once (rows t0+tt*64 .. +63), optional BN fold
    #pragma unroll
    for (int j = 0; j < 4; ++j) {
        int idx = j * 1024 + threadIdx.x * 4;
        int r = idx >> 6, ci = idx & 63;
        int tg = t0 + tt * 64 + r; if (tg > T - 1) tg = T - 1;
        float4 v = *(const float4*)&xin[((size_t)b * T + tg) * 256 + g * 64 + ci];
        if (BN) {
            float4 a4 = *(const float4*)&ac[g * 64 + ci];
            float4 c4 = *(const float4*)&ac[256 + g * 64 + ci];
            v.x = fmaf(v.x, a4.x, c4.x);
            v.y = fmaf(v.y, a4.y, c4.y);
            v.z = fmaf(v.z, a4.z, c4.z);
            v.w = fmaf(v.w, a4.w, c4.w);
        }
        *(float4*)&xs[r][ci] = v;
    }

    float* xpb = xp + (size_t)(g * 32 + b) * tcmax * 256;

    for (int kt = 0; kt < 4; ++kt) {
        __syncthreads();   // protects ws from previous iteration / joins xs stage
        // stage W tile for this kt
        #pragma unroll
        for (int j = 0; j < 4; ++j) {
            int idx = j * 1024 + threadIdx.x * 4;
            int r = idx >> 6, ci = idx & 63;
            float4 v = *(const float4*)&Wih[(size_t)((g * 256 + kt * 64 + r) << 6) + ci];
            *(float4*)&ws[r][ci] = v;
        }
        __syncthreads();

        float acc[4][4] = {};
        #pragma unroll
        for (int i4 = 0; i4 < 16; ++i4) {
            float4 xv[4], wv[4];
            #pragma unroll
            for (int q = 0; q < 4; ++q) xv[q] = *(const float4*)&xs[ty * 4 + q][i4 * 4];
            #pragma unroll
            for (int q = 0; q < 4; ++q) wv[q] = *(const float4*)&ws[tx * 4 + q][i4 * 4];
            #pragma unroll
            for (int a = 0; a < 4; ++a)
                #pragma unroll
                for (int c = 0; c < 4; ++c) {
                    acc[a][c] = fmaf(xv[a].x, wv[c].x, acc[a][c]);
                    acc[a][c] = fmaf(xv[a].y, wv[c].y, acc[a][c]);
                    acc[a][c] = fmaf(xv[a].z, wv[c].z, acc[a][c]);
                    acc[a][c] = fmaf(xv[a].w, wv[c].w, acc[a][c]);
                }
        }

        const int kbase = kt * 64 + tx * 4;
        const float4 b4 = *(const float4*)&bias[g * 256 + kbase];
        #pragma unroll
        for (int a = 0; a < 4; ++a) {
            int tloc = tt * 64 + ty * 4 + a;
            if (tloc < tcn) {
                float4 o;
                o.x = acc[a][0] + b4.x;
                o.y = acc[a][1] + b4.y;
                o.z = acc[a][2] + b4.z;
                o.w = acc[a][3] + b4.w;
                *(float4*)&xpb[(size_t)tloc * 256 + kbase] = o;
            }
        }
    }
}

// ============================================================================
// Recurrence, 512 threads / 8 waves per sequence (block = g*32+b).
// Lane map: l = c8 | jh<<3 | gt<<4.  Wave w owns cols w*8..w*8+7.
//   row = gt*64 + col; each lane does a 32-MAC over j in [jh*32, jh*32+32).
// Gate logic fully intra-wave:
//   full = acc + shfl_xor(acc,8)          (jh combine)
//   P    = act * shfl_xor(act,32)         (gt0: i*g)
//   Q    = shfl_xor(P,16)                 (gt1 gets i*g)
//   c'   = f*c + Q                        (valid at gt1)
//   R    = shfl_xor(c',32)                (gt3 gets c')
//   h    = o * tanh(R)                    (valid at gt3)
// One barrier/step, double-buffered hsh, 4-slot rotating xp prefetch.
// Per-col BN stats (s, ss) accumulated in registers, atomicAdd at end.
// ============================================================================
template<int LAYER>
__global__ __launch_bounds__(512, 1)
void rec_xp(const float* __restrict__ xp,     // (128, tcmax, 256)
            const float* __restrict__ Whh,    // (G,256,64)
            float* __restrict__ out,          // (B,T,256)
            float* __restrict__ stateh, float* __restrict__ statec,
            float* __restrict__ sums,         // [512] s|ss
            int t0, int t1, int tcmax)
{
    const int blk = blockIdx.x;          // g*32+b
    const int g = blk >> 5, b = blk & 31;
    const int tid = threadIdx.x;
    const int w = tid >> 6, l = tid & 63;
    const int c8 = l & 7;
    const int jh = (l >> 3) & 1;
    const int gt = l >> 4;
    const int col = w * 8 + c8;          // 0..63
    const int row = gt * 64 + col;       // 0..255

    __shared__ __align__(16) float hsh[2][64];

    // 32 weights for this lane's (row, j-half)
    float whh[32];
    {
        const float4* wp = (const float4*)&Whh[(size_t)((g * 256 + row) << 6) + jh * 32];
        #pragma unroll
        for (int i = 0; i < 8; ++i) {
            float4 v = wp[i];
            whh[4*i] = v.x; whh[4*i+1] = v.y; whh[4*i+2] = v.z; whh[4*i+3] = v.w;
        }
    }
    // activation constants: gt==2 -> tanh, else sigmoid
    const float m  = (gt == 2) ? 2.f : 1.f;
    const float A  = (gt == 2) ? 2.f : 1.f;
    const float Bc = (gt == 2) ? -1.f : 0.f;

    float cst;      // valid at gt1 lanes
    if (t0 == 0) {
        cst = 0.f;
        if (tid < 64) hsh[0][tid] = 0.f;
    } else {
        cst = statec[blk * 64 + col];
        if (tid < 64) hsh[0][tid] = stateh[blk * 64 + tid];
    }

    const float* xpb = xp + (size_t)blk * tcmax * 256 + row;
    float p[4];
    #pragma unroll
    for (int j = 0; j < 4; ++j) {
        int tp = t0 + j; if (tp > t1 - 1) tp = t1 - 1;
        p[j] = xpb[(size_t)(tp - t0) * 256];
    }

    float hl = 0.f, st_s = 0.f, st_ss = 0.f;
    __syncthreads();

    const int nsteps = t1 - t0;   // always multiple of 4
    for (int s4 = 0; s4 < nsteps; s4 += 4) {
        #pragma unroll
        for (int j = 0; j < 4; ++j) {
            const int cur = j & 1;
            // half mat-vec: 8 float4 broadcast-ish reads (2 addrs/wave = free)
            float a0 = 0.f, a1 = 0.f, a2 = 0.f, a3 = 0.f;
            const float4* hv = (const float4*)&hsh[cur][jh * 32];
            #pragma unroll
            for (int q = 0; q < 8; ++q) {
                float4 z = hv[q];
                a0 = fmaf(whh[4*q],   z.x, a0);
                a1 = fmaf(whh[4*q+1], z.y, a1);
                a2 = fmaf(whh[4*q+2], z.z, a2);
                a3 = fmaf(whh[4*q+3], z.w, a3);
            }
            float acc = (a0 + a1) + (a2 + a3);
            float full = acc + __shfl_xor(acc, 8);     // jh combine
            float pre = full + p[j];                   // xp includes bias
            // refill slot j (used 4 steps later)
            {
                int tp = t0 + s4 + j + 4; if (tp > t1 - 1) tp = t1 - 1;
                p[j] = xpb[(size_t)(tp - t0) * 256];
            }
            float act = A / (1.f + __expf(-m * pre)) + Bc;
            float P = act * __shfl_xor(act, 32);       // gt0: i*g
            float Q = __shfl_xor(P, 16);               // gt1: i*g
            cst = fmaf(act, cst, Q);                   // gt1: c' = f*c + i*g
            float R = __shfl_xor(cst, 32);             // gt3: c'
            float h = act * tanh_f(R);                 // gt3: o * tanh(c')
            if (gt == 3 && jh == 0) {
                hsh[cur ^ 1][col] = h;
                int t = t0 + s4 + j;
                if (LAYER == 1) out[((size_t)b * T + t) * 256 + col * 4 + g] = h;
                else            out[((size_t)b * T + t) * 256 + g * 64 + col] = h;
                st_s += h;
                st_ss = fmaf(h, h, st_ss);
                hl = h;
            }
            __syncthreads();
        }
    }
    if (gt == 3 && jh == 0) {
        stateh[blk * 64 + col] = hl;
        int f = (LAYER == 1) ? (col * 4 + g) : (g * 64 + col);
        atomicAdd(&sums[f], st_s);
        atomicAdd(&sums[256 + f], st_ss);
    }
    if (gt == 1 && jh == 0) {
        statec[blk * 64 + col] = cst;
    }
}

// ============================================================================
// Fallback (proven round-1): fused rec kernel, used only if ws is too small.
// ============================================================================
template<int LAYER>
__global__ __launch_bounds__(256, 1)
void rec_kernel(const float* __restrict__ xin,
                const float* __restrict__ Wih,
                const float* __restrict__ Whh,
                const float* __restrict__ bias,
                const float* __restrict__ bnac,
                float* __restrict__ out)
{
    const int g = blockIdx.x & 3;
    const int b = blockIdx.x >> 2;
    const int k = threadIdx.x;

    __shared__ __align__(16) float xsh[2][64];
    __shared__ __align__(16) float hsh[64];
    __shared__ __align__(16) float gsh[256];

    float wih[64], whh[64];
    {
        const float4* wi = (const float4*)(Wih + (size_t)(g * 256 + k) * 64);
        const float4* wh = (const float4*)(Whh + (size_t)(g * 256 + k) * 64);
        #pragma unroll
        for (int i = 0; i < 16; ++i) {
            float4 v = wi[i];
            wih[4*i] = v.x; wih[4*i+1] = v.y; wih[4*i+2] = v.z; wih[4*i+3] = v.w;
            float4 u = wh[i];
            whh[4*i] = u.x; whh[4*i+1] = u.y; whh[4*i+2] = u.z; whh[4*i+3] = u.w;
        }
    }
    const float bk = bias[g * 256 + k];
    const long rowbase = (long)b * T;
    const int  colbase = g * 64;

    float c = 0.f, af = 1.f, cf = 0.f;
    float xa = 0.f, xb = 0.f;

    if (k < 64) {
        if (LAYER == 2) { af = bnac[colbase + k]; cf = bnac[256 + colbase + k]; }
        hsh[k] = 0.f;
        float x0 = xin[(rowbase + 0) * 256 + colbase + k];
        xsh[0][k] = (LAYER == 2) ? fmaf(x0, af, cf) : x0;
        xa = xin[(rowbase + 1) * 256 + colbase + k];
        xb = xin[(rowbase + 2) * 256 + colbase + k];
    }
    __syncthreads();

    for (int t = 0; t < T; ++t) {
        const int cur = t & 1;
        float xn = 0.f;
        if (k < 64) {
            int tp = t + 3; if (tp > T - 1) tp = T - 1;
            xn = xin[(rowbase + tp) * 256 + colbase + k];
        }
        const float* xs = xsh[cur];
        float a0 = 0.f, a1 = 0.f, a2 = 0.f, a3 = 0.f;
        #pragma unroll
        for (int i = 0; i < 64; i += 4) {
            a0 = fmaf(wih[i],     xs[i],     a0);
            a1 = fmaf(wih[i + 1], xs[i + 1], a1);
            a2 = fmaf(wih[i + 2], xs[i + 2], a2);
            a3 = fmaf(wih[i + 3], xs[i + 3], a3);
        }
        #pragma unroll
        for (int jq = 0; jq < 64; jq += 4) {
            a0 = fmaf(whh[jq],     hsh[jq],     a0);
            a1 = fmaf(whh[jq + 1], hsh[jq + 1], a1);
            a2 = fmaf(whh[jq + 2], hsh[jq + 2], a2);
            a3 = fmaf(whh[jq + 3], hsh[jq + 3], a3);
        }
        const float acc = bk + ((a0 + a1) + (a2 + a3));
        const float act = (k >= 128 && k < 192) ? tanh_f(acc) : sigm(acc);
        gsh[k] = act;
        __syncthreads();

        if (k < 64) {
            const float ig = gsh[k];
            const float fg = gsh[64 + k];
            const float gg = gsh[128 + k];
            const float og = gsh[192 + k];
            c = fmaf(fg, c, ig * gg);
            const float h = og * tanh_f(c);
            hsh[k] = h;
            const long rrow = rowbase + t;
            if (LAYER == 1) out[rrow * 256 + k * 4 + g] = h;
            else            out[rrow * 256 + colbase + k] = h;
            xsh[cur ^ 1][k] = fmaf(xa, af, cf);
            xa = xb; xb = xn;
        }
        __syncthreads();
    }
}

// ============================================================================
// BN stats / apply
// ============================================================================
__global__ void zero_ws(float* sums, int n) {
    int i = blockIdx.x * blockDim.x + threadIdx.x;
    if (i < n) sums[i] = 0.f;
}

__global__ __launch_bounds__(256) void stats_reduce(const float* __restrict__ x,
                                                    float* __restrict__ sums)
{
    float s = 0.f, ss = 0.f;
    for (int r = blockIdx.x; r < ROWS; r += gridDim.x) {
        float v = x[(long)r * 256 + threadIdx.x];
        s += v;
        ss = fmaf(v, v, ss);
    }
    atomicAdd(&sums[threadIdx.x], s);
    atomicAdd(&sums[256 + threadIdx.x], ss);
}

__global__ void stats_finalize(const float* __restrict__ sums,
                               const float* __restrict__ gamma,
                               const float* __restrict__ beta,
                               float* __restrict__ ac)
{
    int f = threadIdx.x;
    const float invN = 1.f / (float)ROWS;
    float mean = sums[f] * invN;
    float var  = fmaf(-mean, mean, sums[256 + f] * invN);
    float a = gamma[f] * rsqrtf(var + 1e-5f);
    ac[f]       = a;
    ac[256 + f] = fmaf(-mean, a, beta[f]);
}

__global__ __launch_bounds__(256) void bn_apply(float* __restrict__ x,
                                                const float* __restrict__ ac)
{
    __shared__ float a_s[256], c_s[256];
    a_s[threadIdx.x] = ac[threadIdx.x];
    c_s[threadIdx.x] = ac[256 + threadIdx.x];
    __syncthreads();
    const long n4 = (long)ROWS * 64;
    for (long i = (long)blockIdx.x * blockDim.x + threadIdx.x; i < n4;
         i += (long)gridDim.x * blockDim.x) {
        float4 v = ((float4*)x)[i];
        int f0 = (int)((i * 4) & 255);
        v.x = fmaf(v.x, a_s[f0],     c_s[f0]);
        v.y = fmaf(v.y, a_s[f0 + 1], c_s[f0 + 1]);
        v.z = fmaf(v.z, a_s[f0 + 2], c_s[f0 + 2]);
        v.w = fmaf(v.w, a_s[f0 + 3], c_s[f0 + 3]);
        ((float4*)x)[i] = v;
    }
}

extern "C" void kernel_launch(void* const* d_in, const int* in_sizes, int n_in,
                              void* d_out, int out_size, void* d_ws, size_t ws_size,
                              hipStream_t stream)
{
    const float* inpt   = (const float*)d_in[0];
    const float* Wih1   = (const float*)d_in[1];
    const float* Whh1   = (const float*)d_in[2];
    const float* b1     = (const float*)d_in[3];
    const float* Wih2   = (const float*)d_in[4];
    const float* Whh2   = (const float*)d_in[5];
    const float* b2     = (const float*)d_in[6];
    const float* gamma1 = (const float*)d_in[7];
    const float* beta1  = (const float*)d_in[8];
    const float* gamma2 = (const float*)d_in[9];
    const float* beta2  = (const float*)d_in[10];
    float* out  = (float*)d_out;

    float* sums1 = (float*)d_ws;        // 512
    float* sums2 = sums1 + 512;         // 512
    float* acbn1 = sums2 + 512;         // 512
    float* acbn2 = acbn1 + 512;         // 512
    float* sth   = acbn2 + 512;         // 8192 (128*64)
    float* stc   = sth + 8192;          // 8192
    float* xpb   = stc + 8192;          // chunk buffer

    const size_t fixedB = (size_t)(4 * 512 + 2 * 8192) * 4;  // 73728
    long availT = ((long)ws_size - (long)fixedB) / (128L * 256L * 4L);
    int Tcmax = (availT >= T) ? T : (int)(availT & ~3L);

    if (Tcmax >= 100) {
        zero_ws<<<4, 256, 0, stream>>>(sums1, 1024);   // zero sums1+sums2

        // ---- layer 1
        for (int t0 = 0; t0 < T; t0 += Tcmax) {
            int tcn = T - t0; if (tcn > Tcmax) tcn = Tcmax;
            int TT = (tcn + 63) / 64;
            xp_proj<false><<<128 * TT, 256, 0, stream>>>(
                inpt, Wih1, b1, nullptr, xpb, t0, tcn, Tcmax, TT);
            rec_xp<1><<<128, 512, 0, stream>>>(xpb, Whh1, out, sth, stc, sums1,
                                               t0, t0 + tcn, Tcmax);
        }
        stats_finalize<<<1, 256, 0, stream>>>(sums1, gamma1, beta1, acbn1);

        // ---- layer 2 (BN1 fused into xp staging)
        for (int t0 = 0; t0 < T; t0 += Tcmax) {
            int tcn = T - t0; if (tcn > Tcmax) tcn = Tcmax;
            int TT = (tcn + 63) / 64;
            xp_proj<true><<<128 * TT, 256, 0, stream>>>(
                out, Wih2, b2, acbn1, xpb, t0, tcn, Tcmax, TT);
            rec_xp<2><<<128, 512, 0, stream>>>(xpb, Whh2, out, sth, stc, sums2,
                                               t0, t0 + tcn, Tcmax);
        }
        stats_finalize<<<1, 256, 0, stream>>>(sums2, gamma2, beta2, acbn2);
        bn_apply<<<2048, 256, 0, stream>>>(out, acbn2);
    } else {
        // ---- fallback: round-1 monolithic path (ws only needs 8 KB)
        zero_ws<<<2, 256, 0, stream>>>(sums1, 512);
        rec_kernel<1><<<G * B, 256, 0, stream>>>(inpt, Wih1, Whh1, b1, nullptr, out);
        stats_reduce<<<256, 256, 0, stream>>>(out, sums1);
        stats_finalize<<<1, 256, 0, stream>>>(sums1, gamma1, beta1, acbn1);
        rec_kernel<2><<<G * B, 256, 0, stream>>>(out, Wih2, Whh2, b2, acbn1, out);
        zero_ws<<<2, 256, 0, stream>>>(sums2, 512);
        stats_reduce<<<256, 256, 0, stream>>>(out, sums2);
        stats_finalize<<<1, 256, 0, stream>>>(sums2, gamma2, beta2, acbn2);
        bn_apply<<<2048, 256, 0, stream>>>(out, acbn2);
    }
}